// Round 1
// baseline (401.487 us; speedup 1.0000x reference)
//
#include <hip/hip_runtime.h>
#include <stdint.h>

// Problem constants (fixed by setup_inputs)
#define DD   128      // feature dim D
#define TT   64       // time steps
#define BB   8192     // batch
#define NPOW 12       // Taylor degree for expm (||t W|| <= ~1.3 -> remainder ~2e-9)

typedef float  f32x4  __attribute__((ext_vector_type(4)));
typedef __bf16 bf16x8 __attribute__((ext_vector_type(8)));

// RTN-even float -> bf16 bits
__device__ __forceinline__ unsigned short f2bf(float f) {
  unsigned u = __builtin_bit_cast(unsigned, f);
  u += 0x7fffu + ((u >> 16) & 1u);
  return (unsigned short)(u >> 16);
}

// async global->LDS, 16 bytes/lane. LDS dest = wave-uniform base + lane*16.
__device__ __forceinline__ void async_load16(const void* g, void* l) {
  __builtin_amdgcn_global_load_lds(
      (const __attribute__((address_space(1))) unsigned int*)g,
      (__attribute__((address_space(3))) unsigned int*)l,
      16, 0, 0);
}

// ---------------------------------------------------------------------------
// x (fp32) -> xb (bf16 bits), 8192x128, 4 elems/thread
// ---------------------------------------------------------------------------
__global__ void cvt_x_kernel(const float* __restrict__ x, unsigned short* __restrict__ xb) {
  int i = (blockIdx.x * 256 + threadIdx.x) * 4;
  float4 v = *(const float4*)(x + i);
  unsigned long long u =  (unsigned long long)f2bf(v.x)
                       | ((unsigned long long)f2bf(v.y) << 16)
                       | ((unsigned long long)f2bf(v.z) << 32)
                       | ((unsigned long long)f2bf(v.w) << 48);
  *(unsigned long long*)(xb + i) = u;
}

// ---------------------------------------------------------------------------
// Small fp32 matmul stage: for mat in [0,nmat): W^(a+bBase+mat) = W^a * W^(bBase+mat)
// Wp holds W^n at slot (n-2). grid = nmat*8 blocks, 16 rows per block, 256 thr.
// ---------------------------------------------------------------------------
__global__ void powmm_kernel(const float* __restrict__ W, float* __restrict__ Wp,
                             int aPow, int bBase, int dstBase) {
  int mat = blockIdx.x >> 3;
  int rb  = blockIdx.x & 7;
  int bPow = bBase + mat;
  const float* A = (aPow == 1) ? W : (Wp + (aPow - 2) * DD * DD);
  const float* B = (bPow == 1) ? W : (Wp + (bPow - 2) * DD * DD);
  float* C = Wp + (dstBase + mat - 2) * DD * DD;

  __shared__ float Bs[DD * DD];          // 64 KB
  __shared__ float As[16 * DD];          // 8 KB
  for (int i = threadIdx.x; i < DD * DD; i += 256) Bs[i] = B[i];
  for (int i = threadIdx.x; i < 16 * DD; i += 256) As[i] = A[rb * 16 * DD + i];
  __syncthreads();

  int r  = threadIdx.x >> 4;             // 0..15 local row
  int c0 = (threadIdx.x & 15) * 8;       // 8 cols per thread
  float acc[8] = {0.f, 0.f, 0.f, 0.f, 0.f, 0.f, 0.f, 0.f};
  for (int k = 0; k < DD; ++k) {
    float a = As[r * DD + k];
#pragma unroll
    for (int jj = 0; jj < 8; ++jj) acc[jj] += a * Bs[k * DD + c0 + jj];
  }
  int gr = rb * 16 + r;
#pragma unroll
  for (int jj = 0; jj < 8; ++jj) C[gr * DD + c0 + jj] = acc[jj];
}

// ---------------------------------------------------------------------------
// Combine: P_j = I + sum_{n=1..12} (t^n/n!) W^n,  t = j*0.01
// Stored TRANSPOSED as bf16: Pb[j][d][k] = P_j[k][d]  (B^T layout for GEMM)
// grid = 64 (j), 256 threads
// ---------------------------------------------------------------------------
__global__ void combine_kernel(const float* __restrict__ W, const float* __restrict__ Wp,
                               unsigned short* __restrict__ Pb) {
  int j = blockIdx.x;
  double t = (double)j * 0.01;
  float c[NPOW + 1];
  double cc = 1.0;
  for (int n = 1; n <= NPOW; ++n) { cc *= t / (double)n; c[n] = (float)cc; }

  for (int o = threadIdx.x; o < DD * DD; o += 256) {
    int d = o >> 7;        // output col of P_j (row of P^T)
    int k = o & 127;       // contraction index (col of P^T)
    float acc = (k == d) ? 1.0f : 0.0f;
    acc += c[1] * W[k * DD + d];
#pragma unroll
    for (int n = 2; n <= NPOW; ++n) acc += c[n] * Wp[(n - 2) * DD * DD + k * DD + d];
    Pb[j * DD * DD + o] = f2bf(acc);
  }
}

// ---------------------------------------------------------------------------
// Main GEMM: out[b, j*128+d] = sum_k xb[b,k] * P_j[k,d]
// grid (64 b-tiles, 64 j), 256 threads (4 waves), 128x128 tile, K=128 (4 k-steps)
// LDS: A-tile 32 KB + B-tile 32 KB, staged via global_load_lds w/ XOR-16B swizzle
// ---------------------------------------------------------------------------
__global__ __launch_bounds__(256) void gemm_kernel(
    const unsigned short* __restrict__ xb,   // 8192 x 128 bf16, row-major
    const unsigned short* __restrict__ Pb,   // 64 x (128 d x 128 k) bf16 (P^T per j)
    float* __restrict__ out) {               // 8192 x 8192 fp32
  __shared__ __attribute__((aligned(16))) unsigned short Al[DD * DD];
  __shared__ __attribute__((aligned(16))) unsigned short Bl[DD * DD];

  const int bt   = blockIdx.x;
  const int j    = blockIdx.y;
  const int tid  = threadIdx.x;
  const int w    = tid >> 6;       // wave 0..3
  const int l    = tid & 63;       // lane
  const int quad = l >> 4;         // 0..3
  const int li   = l & 15;         // lane-in-quad

  const unsigned short* gA = xb + bt * DD * DD;
  const unsigned short* gB = Pb + j * DD * DD;

  // Stage both tiles. chunk index ci in [0,32): wave-uniform LDS base = ci*1024B.
  // LDS slot (row, sc) holds global 16B-chunk (row, sc ^ (row & 15)).
#pragma unroll
  for (int i = 0; i < 8; ++i) {
    int ci  = i * 4 + w;
    int row = ci * 4 + quad;            // 0..127
    int cc  = li ^ (row & 15);          // source chunk within row
    async_load16(gA + row * DD + cc * 8, (void*)(Al + ci * 512));
    async_load16(gB + row * DD + cc * 8, (void*)(Bl + ci * 512));
  }
  __syncthreads();

  const int mq = (w >> 1) * 64;        // wave's 64x64 quadrant
  const int nq = (w & 1) * 64;

  f32x4 acc[4][4];
#pragma unroll
  for (int mt = 0; mt < 4; ++mt)
#pragma unroll
    for (int nt = 0; nt < 4; ++nt) acc[mt][nt] = (f32x4){0.f, 0.f, 0.f, 0.f};

#pragma unroll
  for (int ks = 0; ks < 4; ++ks) {
    bf16x8 af[4], bf[4];
#pragma unroll
    for (int mt = 0; mt < 4; ++mt) {
      int row = mq + mt * 16 + li;                    // m index
      int sc  = (ks * 4 + quad) ^ (row & 15);         // swizzled chunk
      af[mt] = *(const bf16x8*)(Al + row * DD + sc * 8);
    }
#pragma unroll
    for (int nt = 0; nt < 4; ++nt) {
      int row = nq + nt * 16 + li;                    // n index (P^T row)
      int sc  = (ks * 4 + quad) ^ (row & 15);
      bf[nt] = *(const bf16x8*)(Bl + row * DD + sc * 8);
    }
#pragma unroll
    for (int mt = 0; mt < 4; ++mt)
#pragma unroll
      for (int nt = 0; nt < 4; ++nt)
        acc[mt][nt] = __builtin_amdgcn_mfma_f32_16x16x32_bf16(af[mt], bf[nt], acc[mt][nt], 0, 0, 0);
  }

  // Epilogue: D layout col = lane&15, row = quad*4 + reg
  float* o = out + (size_t)(bt * DD) * (TT * DD) + j * DD;
#pragma unroll
  for (int mt = 0; mt < 4; ++mt) {
#pragma unroll
    for (int nt = 0; nt < 4; ++nt) {
      int col = nq + nt * 16 + li;
#pragma unroll
      for (int r = 0; r < 4; ++r) {
        int row = mq + mt * 16 + quad * 4 + r;
        o[(size_t)row * (TT * DD) + col] = acc[mt][nt][r];
      }
    }
  }
}

// ---------------------------------------------------------------------------
extern "C" void kernel_launch(void* const* d_in, const int* in_sizes, int n_in,
                              void* d_out, int out_size, void* d_ws, size_t ws_size,
                              hipStream_t stream) {
  const float* x = (const float*)d_in[0];
  const float* W = (const float*)d_in[1];
  float* out = (float*)d_out;

  // Workspace carve-up (all 16B aligned):
  //   Wp: 11 fp32 128x128 matrices (W^2..W^12)  = 720896 B
  //   Pb: 64 * 128*128 bf16 (P_j transposed)    = 2 MiB
  //   xb: 8192*128 bf16                          = 2 MiB
  float* Wp = (float*)d_ws;
  unsigned short* Pb = (unsigned short*)((char*)d_ws + (NPOW - 1) * DD * DD * sizeof(float));
  unsigned short* xb = Pb + TT * DD * DD;

  cvt_x_kernel<<<BB * DD / (256 * 4), 256, 0, stream>>>(x, xb);

  // log-depth power ladder: W2 | W3,W4 | W5..W8 | W9..W12
  powmm_kernel<<< 8, 256, 0, stream>>>(W, Wp, 1, 1, 2);
  powmm_kernel<<<16, 256, 0, stream>>>(W, Wp, 2, 1, 3);
  powmm_kernel<<<32, 256, 0, stream>>>(W, Wp, 4, 1, 5);
  powmm_kernel<<<32, 256, 0, stream>>>(W, Wp, 8, 1, 9);

  combine_kernel<<<TT, 256, 0, stream>>>(W, Wp, Pb);

  gemm_kernel<<<dim3(BB / DD, TT), 256, 0, stream>>>(xb, Pb, out);
}

// Round 2
// 344.446 us; speedup vs baseline: 1.1656x; 1.1656x over previous
//
#include <hip/hip_runtime.h>
#include <stdint.h>

// Problem constants (fixed by setup_inputs)
#define DD   128      // feature dim D
#define TT   64       // time steps
#define BB   8192     // batch
#define NPOW 8        // Taylor degree for expm: ||tW||<=~1.3 -> remainder 1.3^9/9! ~ 3e-5

typedef float  f32x4  __attribute__((ext_vector_type(4)));
typedef __bf16 bf16x8 __attribute__((ext_vector_type(8)));

// RTN-even float -> bf16 bits
__device__ __forceinline__ unsigned short f2bf(float f) {
  unsigned u = __builtin_bit_cast(unsigned, f);
  u += 0x7fffu + ((u >> 16) & 1u);
  return (unsigned short)(u >> 16);
}

// ---------------------------------------------------------------------------
// x (fp32) -> xb (bf16 bits), 8192x128, 4 elems/thread, fully coalesced
// ---------------------------------------------------------------------------
__global__ void cvt_x_kernel(const float* __restrict__ x, unsigned short* __restrict__ xb) {
  int i = (blockIdx.x * 256 + threadIdx.x) * 4;
  float4 v = *(const float4*)(x + i);
  unsigned long long u =  (unsigned long long)f2bf(v.x)
                       | ((unsigned long long)f2bf(v.y) << 16)
                       | ((unsigned long long)f2bf(v.z) << 32)
                       | ((unsigned long long)f2bf(v.w) << 48);
  *(unsigned long long*)(xb + i) = u;
}

// ---------------------------------------------------------------------------
// Wt = W^T (128x128 fp32). grid 16 blocks of 32x32 tiles, 256 threads.
// Wt goes to Wp slot 0 (power-1 slot). All later ladder work is on W^T, so
// (W^T)^n = (W^n)^T and combine reads/writes are coalesced.
// ---------------------------------------------------------------------------
__global__ void transpose_kernel(const float* __restrict__ W, float* __restrict__ Wt) {
  __shared__ float t[32][33];
  int bx = blockIdx.x & 3, by = blockIdx.x >> 2;
  int r = threadIdx.x >> 3;          // 0..31
  int c = (threadIdx.x & 7) * 4;     // 4 cols/thread
  float4 v = *(const float4*)(W + (by * 32 + r) * DD + bx * 32 + c);
  t[r][c] = v.x; t[r][c + 1] = v.y; t[r][c + 2] = v.z; t[r][c + 3] = v.w;
  __syncthreads();
  float4 o = { t[c + 0][r], t[c + 1][r], t[c + 2][r], t[c + 3][r] };
  *(float4*)(Wt + (bx * 32 + r) * DD + by * 32 + c) = o;
}

// ---------------------------------------------------------------------------
// fp32 power ladder on W^T. Wp slot (n-1) holds (W^T)^n.
// For mat in [0,nmat): slot(aPow + bBase + mat) = slot(aPow) * slot(bBase+mat)
// grid = nmat*16 blocks (16 row-blocks of 8 rows), 256 threads, float4 I/O.
// ---------------------------------------------------------------------------
__global__ __launch_bounds__(256) void powmm_kernel(float* __restrict__ Wp,
                                                    int aPow, int bBase, int dstBase) {
  int mat = blockIdx.x >> 4;
  int rb  = blockIdx.x & 15;
  const float* A = Wp + (aPow - 1) * DD * DD;
  const float* B = Wp + (bBase + mat - 1) * DD * DD;
  float* C = Wp + (dstBase + mat - 1) * DD * DD;

  __shared__ float Bs[DD * DD];      // 64 KB
  __shared__ float As[8 * DD];       // 4 KB
  for (int i = threadIdx.x; i < DD * DD / 4; i += 256)
    ((float4*)Bs)[i] = ((const float4*)B)[i];
  for (int i = threadIdx.x; i < 8 * DD / 4; i += 256)
    ((float4*)As)[i] = ((const float4*)(A + rb * 8 * DD))[i];
  __syncthreads();

  int r  = threadIdx.x >> 5;         // 0..7 local row
  int c0 = (threadIdx.x & 31) * 4;   // 4 cols/thread
  f32x4 acc = {0.f, 0.f, 0.f, 0.f};
  for (int k = 0; k < DD; ++k) {
    float a = As[r * DD + k];
    f32x4 b = *(const f32x4*)(Bs + k * DD + c0);
    acc += a * b;
  }
  *(f32x4*)(C + (rb * 8 + r) * DD + c0) = acc;
}

// ---------------------------------------------------------------------------
// Combine: P_j^T = I + sum_{n=1..8} (t^n/n!) (W^T)^n,  t = j*0.01, bf16 out.
// Fully coalesced float4 reads + 8B writes. grid = 64*16 blocks, 256 threads.
// ---------------------------------------------------------------------------
__global__ __launch_bounds__(256) void combine_kernel(const float* __restrict__ Wp,
                                                      unsigned short* __restrict__ Pb) {
  int j    = blockIdx.x >> 4;
  int part = blockIdx.x & 15;
  float c[NPOW];
  double t = (double)j * 0.01, cc = 1.0;
  for (int n = 1; n <= NPOW; ++n) { cc *= t / (double)n; c[n - 1] = (float)cc; }

  int e0 = part * 1024 + threadIdx.x * 4;   // element offset within 128x128
  f32x4 acc;
#pragma unroll
  for (int i = 0; i < 4; ++i) {
    int e = e0 + i;
    acc[i] = ((e >> 7) == (e & 127)) ? 1.0f : 0.0f;   // identity
  }
#pragma unroll
  for (int n = 0; n < NPOW; ++n) {
    f32x4 w = *(const f32x4*)(Wp + n * DD * DD + e0);
    acc += c[n] * w;
  }
  unsigned long long u =  (unsigned long long)f2bf(acc[0])
                       | ((unsigned long long)f2bf(acc[1]) << 16)
                       | ((unsigned long long)f2bf(acc[2]) << 32)
                       | ((unsigned long long)f2bf(acc[3]) << 48);
  *(unsigned long long*)(Pb + j * DD * DD + e0) = u;
}

// ---------------------------------------------------------------------------
// Main GEMM: out[b, j*128+d] = sum_k xb[b,k] * P_j[k,d]
// NO LDS, NO barriers: xb (2 MiB) + Pb (2 MiB) are L2-resident; MFMA fragments
// are 16B-contiguous in both operands -> direct global_load_dwordx4 per lane.
// grid (64 b-tiles, 64 j), 256 threads (4 waves), 128x128 tile per block.
// ---------------------------------------------------------------------------
__global__ __launch_bounds__(256) void gemm_kernel(
    const unsigned short* __restrict__ xb,   // 8192 x 128 bf16 row-major
    const unsigned short* __restrict__ Pb,   // 64 x (128 d x 128 k) bf16 (P^T per j)
    float* __restrict__ out) {               // 8192 x (64*128) fp32
  const int bt   = blockIdx.x;
  const int j    = blockIdx.y;
  const int tid  = threadIdx.x;
  const int w    = tid >> 6;       // wave 0..3
  const int l    = tid & 63;
  const int quad = l >> 4;         // 0..3
  const int li   = l & 15;

  const int mq = (w >> 1) * 64;    // wave's 64x64 quadrant
  const int nq = (w & 1) * 64;

  const unsigned short* gA = xb + bt * DD * DD;
  const unsigned short* gB = Pb + j * DD * DD;

  f32x4 acc[4][4];
#pragma unroll
  for (int mt = 0; mt < 4; ++mt)
#pragma unroll
    for (int nt = 0; nt < 4; ++nt) acc[mt][nt] = (f32x4){0.f, 0.f, 0.f, 0.f};

#pragma unroll
  for (int ks = 0; ks < 4; ++ks) {
    bf16x8 af[4], bf[4];
#pragma unroll
    for (int mt = 0; mt < 4; ++mt)
      af[mt] = *(const bf16x8*)(gA + (mq + mt * 16 + li) * DD + ks * 32 + quad * 8);
#pragma unroll
    for (int nt = 0; nt < 4; ++nt)
      bf[nt] = *(const bf16x8*)(gB + (nq + nt * 16 + li) * DD + ks * 32 + quad * 8);
#pragma unroll
    for (int mt = 0; mt < 4; ++mt)
#pragma unroll
      for (int nt = 0; nt < 4; ++nt)
        acc[mt][nt] = __builtin_amdgcn_mfma_f32_16x16x32_bf16(af[mt], bf[nt], acc[mt][nt], 0, 0, 0);
  }

  // Epilogue (validated round 1): D layout col = lane&15, row = quad*4 + reg.
  // Streaming output -> nontemporal stores.
  float* o = out + (size_t)(bt * DD) * (TT * DD) + j * DD;
#pragma unroll
  for (int mt = 0; mt < 4; ++mt) {
#pragma unroll
    for (int nt = 0; nt < 4; ++nt) {
      int col = nq + nt * 16 + li;
#pragma unroll
      for (int r = 0; r < 4; ++r) {
        int row = mq + mt * 16 + quad * 4 + r;
        __builtin_nontemporal_store(acc[mt][nt][r], &o[row * (TT * DD) + col]);
      }
    }
  }
}

// ---------------------------------------------------------------------------
extern "C" void kernel_launch(void* const* d_in, const int* in_sizes, int n_in,
                              void* d_out, int out_size, void* d_ws, size_t ws_size,
                              hipStream_t stream) {
  const float* x = (const float*)d_in[0];
  const float* W = (const float*)d_in[1];
  float* out = (float*)d_out;

  // Workspace: Wp = 8 fp32 128x128 slots ((W^T)^1..(W^T)^8) = 512 KB,
  //            Pb = 64 * 128*128 bf16 = 2 MiB,  xb = 8192*128 bf16 = 2 MiB
  float* Wp = (float*)d_ws;
  unsigned short* Pb = (unsigned short*)((char*)d_ws + NPOW * DD * DD * sizeof(float));
  unsigned short* xb = Pb + TT * DD * DD;

  cvt_x_kernel<<<BB * DD / (256 * 4), 256, 0, stream>>>(x, xb);
  transpose_kernel<<<16, 256, 0, stream>>>(W, Wp);          // slot 0 = W^T

  // log-depth ladder on W^T: n=2 | n=3,4 | n=5..8
  powmm_kernel<<<16, 256, 0, stream>>>(Wp, 1, 1, 2);
  powmm_kernel<<<32, 256, 0, stream>>>(Wp, 2, 1, 3);
  powmm_kernel<<<64, 256, 0, stream>>>(Wp, 4, 1, 5);

  combine_kernel<<<TT * 16, 256, 0, stream>>>(Wp, Pb);

  gemm_kernel<<<dim3(BB / DD, TT), 256, 0, stream>>>(xb, Pb, out);
}

// Round 3
// 341.144 us; speedup vs baseline: 1.1769x; 1.0097x over previous
//
#include <hip/hip_runtime.h>
#include <stdint.h>

// Problem constants (fixed by setup_inputs)
#define DD   128      // feature dim D
#define TT   64       // time steps
#define BB   8192     // batch
#define NPOW 8        // Taylor degree for expm: ||tW||<=~1.3 -> remainder 1.3^9/9! ~ 3e-5

typedef float  f32x4  __attribute__((ext_vector_type(4)));
typedef __bf16 bf16x8 __attribute__((ext_vector_type(8)));

// RTN-even float -> bf16 bits
__device__ __forceinline__ unsigned short f2bf(float f) {
  unsigned u = __builtin_bit_cast(unsigned, f);
  u += 0x7fffu + ((u >> 16) & 1u);
  return (unsigned short)(u >> 16);
}

// ---------------------------------------------------------------------------
// x (fp32) -> xb (bf16 bits), 8192x128, 4 elems/thread, fully coalesced
// ---------------------------------------------------------------------------
__global__ void cvt_x_kernel(const float* __restrict__ x, unsigned short* __restrict__ xb) {
  int i = (blockIdx.x * 256 + threadIdx.x) * 4;
  float4 v = *(const float4*)(x + i);
  unsigned long long u =  (unsigned long long)f2bf(v.x)
                       | ((unsigned long long)f2bf(v.y) << 16)
                       | ((unsigned long long)f2bf(v.z) << 32)
                       | ((unsigned long long)f2bf(v.w) << 48);
  *(unsigned long long*)(xb + i) = u;
}

// ---------------------------------------------------------------------------
// Wt = W^T (128x128 fp32). grid 16 blocks of 32x32 tiles, 256 threads.
// Wt goes to Wp slot 0. Ladder runs on W^T so (W^T)^n = (W^n)^T and combine
// reads/writes stay coalesced.
// ---------------------------------------------------------------------------
__global__ void transpose_kernel(const float* __restrict__ W, float* __restrict__ Wt) {
  __shared__ float t[32][33];
  int bx = blockIdx.x & 3, by = blockIdx.x >> 2;
  int r = threadIdx.x >> 3;          // 0..31
  int c = (threadIdx.x & 7) * 4;     // 4 cols/thread
  float4 v = *(const float4*)(W + (by * 32 + r) * DD + bx * 32 + c);
  t[r][c] = v.x; t[r][c + 1] = v.y; t[r][c + 2] = v.z; t[r][c + 3] = v.w;
  __syncthreads();
  float4 o = { t[c + 0][r], t[c + 1][r], t[c + 2][r], t[c + 3][r] };
  *(float4*)(Wt + (bx * 32 + r) * DD + by * 32 + c) = o;
}

// ---------------------------------------------------------------------------
// fp32 power ladder on W^T. Wp slot (n-1) holds (W^T)^n.
// grid = nmat*16 blocks (16 row-blocks of 8 rows), 256 threads, float4 I/O.
// ---------------------------------------------------------------------------
__global__ __launch_bounds__(256) void powmm_kernel(float* __restrict__ Wp,
                                                    int aPow, int bBase, int dstBase) {
  int mat = blockIdx.x >> 4;
  int rb  = blockIdx.x & 15;
  const float* A = Wp + (aPow - 1) * DD * DD;
  const float* B = Wp + (bBase + mat - 1) * DD * DD;
  float* C = Wp + (dstBase + mat - 1) * DD * DD;

  __shared__ float Bs[DD * DD];      // 64 KB
  __shared__ float As[8 * DD];       // 4 KB
  for (int i = threadIdx.x; i < DD * DD / 4; i += 256)
    ((float4*)Bs)[i] = ((const float4*)B)[i];
  for (int i = threadIdx.x; i < 8 * DD / 4; i += 256)
    ((float4*)As)[i] = ((const float4*)(A + rb * 8 * DD))[i];
  __syncthreads();

  int r  = threadIdx.x >> 5;         // 0..7 local row
  int c0 = (threadIdx.x & 31) * 4;   // 4 cols/thread
  f32x4 acc = {0.f, 0.f, 0.f, 0.f};
  for (int k = 0; k < DD; ++k) {
    float a = As[r * DD + k];
    f32x4 b = *(const f32x4*)(Bs + k * DD + c0);
    acc += a * b;
  }
  *(f32x4*)(C + (rb * 8 + r) * DD + c0) = acc;
}

// ---------------------------------------------------------------------------
// Combine: P_j^T = I + sum_{n=1..8} (t^n/n!) (W^T)^n,  t = j*0.01, bf16 out.
// Fully coalesced float4 reads + 8B writes. grid = 64*16 blocks, 256 threads.
// ---------------------------------------------------------------------------
__global__ __launch_bounds__(256) void combine_kernel(const float* __restrict__ Wp,
                                                      unsigned short* __restrict__ Pb) {
  int j    = blockIdx.x >> 4;
  int part = blockIdx.x & 15;
  float c[NPOW];
  double t = (double)j * 0.01, cc = 1.0;
  for (int n = 1; n <= NPOW; ++n) { cc *= t / (double)n; c[n - 1] = (float)cc; }

  int e0 = part * 1024 + threadIdx.x * 4;   // element offset within 128x128
  f32x4 acc;
#pragma unroll
  for (int i = 0; i < 4; ++i) {
    int e = e0 + i;
    acc[i] = ((e >> 7) == (e & 127)) ? 1.0f : 0.0f;   // identity
  }
#pragma unroll
  for (int n = 0; n < NPOW; ++n) {
    f32x4 w = *(const f32x4*)(Wp + n * DD * DD + e0);
    acc += c[n] * w;
  }
  unsigned long long u =  (unsigned long long)f2bf(acc[0])
                       | ((unsigned long long)f2bf(acc[1]) << 16)
                       | ((unsigned long long)f2bf(acc[2]) << 32)
                       | ((unsigned long long)f2bf(acc[3]) << 48);
  *(unsigned long long*)(Pb + j * DD * DD + e0) = u;
}

// ---------------------------------------------------------------------------
// Main GEMM: out[b, j*128+d] = sum_k xb[b,k] * P_j[k,d]
// Operands direct from L2 (xb 2MiB + Pb 2MiB resident); no staging barriers.
// Epilogue: LDS transpose (2 chunks of 64x132) -> float4 nontemporal stores
// of full 128B lines (avoids write-allocate fetch of the output stream).
// grid (64 b-tiles, 64 j), 256 threads (4 waves), 128x128 tile per block.
// ---------------------------------------------------------------------------
__global__ __launch_bounds__(256) void gemm_kernel(
    const unsigned short* __restrict__ xb,   // 8192 x 128 bf16 row-major
    const unsigned short* __restrict__ Pb,   // 64 x (128 d x 128 k) bf16 (P^T per j)
    float* __restrict__ out) {               // 8192 x (64*128) fp32
  __shared__ float ct[64 * 132];             // 33.8 KB epilogue staging

  const int bt   = blockIdx.x;
  const int j    = blockIdx.y;
  const int tid  = threadIdx.x;
  const int w    = tid >> 6;       // wave 0..3
  const int l    = tid & 63;
  const int quad = l >> 4;         // 0..3
  const int li   = l & 15;

  const int mq = (w >> 1) * 64;    // wave's 64x64 quadrant
  const int nq = (w & 1) * 64;

  const unsigned short* gA = xb + bt * DD * DD;
  const unsigned short* gB = Pb + j * DD * DD;

  f32x4 acc[4][4];
#pragma unroll
  for (int mt = 0; mt < 4; ++mt)
#pragma unroll
    for (int nt = 0; nt < 4; ++nt) acc[mt][nt] = (f32x4){0.f, 0.f, 0.f, 0.f};

#pragma unroll
  for (int ks = 0; ks < 4; ++ks) {
    bf16x8 af[4], bf[4];
#pragma unroll
    for (int mt = 0; mt < 4; ++mt)
      af[mt] = *(const bf16x8*)(gA + (mq + mt * 16 + li) * DD + ks * 32 + quad * 8);
#pragma unroll
    for (int nt = 0; nt < 4; ++nt)
      bf[nt] = *(const bf16x8*)(gB + (nq + nt * 16 + li) * DD + ks * 32 + quad * 8);
#pragma unroll
    for (int mt = 0; mt < 4; ++mt)
#pragma unroll
      for (int nt = 0; nt < 4; ++nt)
        acc[mt][nt] = __builtin_amdgcn_mfma_f32_16x16x32_bf16(af[mt], bf[nt], acc[mt][nt], 0, 0, 0);
  }

  // ---- Epilogue ----
  // D layout (validated): col = nq + nt*16 + (lane&15), row = mq + mt*16 + quad*4 + r
  // Chunk c covers global rows c*64 .. c*64+63 (owned by waves with w>>1 == c).
  // LDS row padded to 132 floats: scalar writes land 2 lanes/bank (free).
  const size_t orow = (size_t)(TT * DD);
  float* obase = out + (size_t)(bt * DD) * orow + j * DD;
#pragma unroll
  for (int c = 0; c < 2; ++c) {
    __syncthreads();
    if ((w >> 1) == c) {
#pragma unroll
      for (int mt = 0; mt < 4; ++mt)
#pragma unroll
        for (int nt = 0; nt < 4; ++nt)
#pragma unroll
          for (int r = 0; r < 4; ++r)
            ct[(mt * 16 + quad * 4 + r) * 132 + nq + nt * 16 + li] = acc[mt][nt][r];
    }
    __syncthreads();
    // 64 rows x 128 cols = 2048 float4; 8 per thread; each wave-instr writes
    // 2 rows x 512B contiguous -> full 128B lines, no allocate-fetch.
#pragma unroll
    for (int p = 0; p < 8; ++p) {
      int idx = p * 256 + tid;
      int rl  = idx >> 5;              // local row 0..63
      int c4  = (idx & 31) * 4;        // col 0..124 step 4
      f32x4 v = *(const f32x4*)(ct + rl * 132 + c4);
      __builtin_nontemporal_store(v, (f32x4*)(obase + (size_t)(c * 64 + rl) * orow + c4));
    }
  }
}

// ---------------------------------------------------------------------------
extern "C" void kernel_launch(void* const* d_in, const int* in_sizes, int n_in,
                              void* d_out, int out_size, void* d_ws, size_t ws_size,
                              hipStream_t stream) {
  const float* x = (const float*)d_in[0];
  const float* W = (const float*)d_in[1];
  float* out = (float*)d_out;

  // Workspace: Wp = 8 fp32 128x128 slots ((W^T)^1..(W^T)^8) = 512 KB,
  //            Pb = 64 * 128*128 bf16 = 2 MiB,  xb = 8192*128 bf16 = 2 MiB
  float* Wp = (float*)d_ws;
  unsigned short* Pb = (unsigned short*)((char*)d_ws + NPOW * DD * DD * sizeof(float));
  unsigned short* xb = Pb + TT * DD * DD;

  cvt_x_kernel<<<BB * DD / (256 * 4), 256, 0, stream>>>(x, xb);
  transpose_kernel<<<16, 256, 0, stream>>>(W, Wp);          // slot 0 = W^T

  // log-depth ladder on W^T: n=2 | n=3,4 | n=5..8
  powmm_kernel<<<16, 256, 0, stream>>>(Wp, 1, 1, 2);
  powmm_kernel<<<32, 256, 0, stream>>>(Wp, 2, 1, 3);
  powmm_kernel<<<64, 256, 0, stream>>>(Wp, 4, 1, 5);

  combine_kernel<<<TT * 16, 256, 0, stream>>>(Wp, Pb);

  gemm_kernel<<<dim3(BB / DD, TT), 256, 0, stream>>>(xb, Pb, out);
}